// Round 1
// baseline (495.716 us; speedup 1.0000x reference)
//
#include <hip/hip_runtime.h>

// ---- problem constants (from reference) ----
#define SEQ      10688      // IMG_LEN + TEXT_LEN
#define IMG_LEN  10368      // 18*24*24
#define TEXT_LEN 320
#define DH       128
#define NHEADS   4
#define SLAB     3456       // 6*24*24 tokens per time-slab
#define SCALEF   0.088388347648318447f   // 1/sqrt(128)
#define KVC      64         // kv chunk rows
#define QTILE    64         // q rows per block (4 waves x 16)
#define NIMGT    162        // IMG_LEN/QTILE image q-tiles per head
#define NTXTT    5          // TEXT_LEN/QTILE text q-tiles per head
#define LKP      136        // K lds pitch (elements): 128 + 8 pad, row = 272B (16B aligned)
#define VTP      72         // V^T lds pitch (elements): 64 + 8 pad, row = 144B (16B aligned)

typedef __bf16 bf16x8 __attribute__((ext_vector_type(8)));
typedef float  f32x4  __attribute__((ext_vector_type(4)));

__device__ __forceinline__ unsigned short f2bf(float a) {
    unsigned u = __float_as_uint(a);
    return (unsigned short)((u + 0x7FFFu + ((u >> 16) & 1u)) >> 16);   // RNE
}
__device__ __forceinline__ unsigned f2bf_pk(float a, float b) {
    return (unsigned)f2bf(a) | ((unsigned)f2bf(b) << 16);
}

__global__ __launch_bounds__(256) void sta_attn(const float* __restrict__ Qg,
                                                const float* __restrict__ Kg,
                                                const float* __restrict__ Vg,
                                                float* __restrict__ Og) {
    __shared__ unsigned short LK[KVC * LKP];   // K chunk, [kv][d] bf16, padded
    __shared__ unsigned short VT[DH * VTP];    // V^T chunk, [d][kv] bf16, padded

    const int tid  = threadIdx.x;
    const int lane = tid & 63;
    const int wv   = tid >> 6;
    const int q    = lane & 15;   // query row within wave's 16 (swapped-MFMA layout)
    const int g    = lane >> 4;   // lane group 0..3

    // block -> (head, qbase). Text tiles (167 chunks) first: longest work starts earliest.
    int b = blockIdx.x;
    int head, qbase, nch, kvb0;
    bool isText;
    if (b < NHEADS * NTXTT) {
        head = b / NTXTT; qbase = IMG_LEN + (b % NTXTT) * QTILE;
        isText = true;  nch = SEQ / KVC;  kvb0 = 0;
    } else {
        int bb = b - NHEADS * NTXTT;
        head = bb / NIMGT; qbase = (bb % NIMGT) * QTILE;
        isText = false; nch = 54 + 5;     // 54 slab chunks + 5 text chunks
        kvb0 = (qbase / SLAB) * SLAB;
    }

    const size_t hoff = (size_t)head * SEQ * DH;
    const float* Qh = Qg + hoff;
    const float* Kh = Kg + hoff;
    const float* Vh = Vg + hoff;

    // ---- load Q fragments (B-operand layout), SCALE folded in ----
    const int qrow = qbase + wv * 16 + q;
    const float* qp = Qh + (size_t)qrow * DH;
    bf16x8 qf[4];
    #pragma unroll
    for (int c = 0; c < 4; ++c) {
        float4 a = *(const float4*)(qp + c * 32 + g * 8);
        float4 d = *(const float4*)(qp + c * 32 + g * 8 + 4);
        union { unsigned u[4]; bf16x8 v; } t;
        t.u[0] = f2bf_pk(a.x * SCALEF, a.y * SCALEF);
        t.u[1] = f2bf_pk(a.z * SCALEF, a.w * SCALEF);
        t.u[2] = f2bf_pk(d.x * SCALEF, d.y * SCALEF);
        t.u[3] = f2bf_pk(d.z * SCALEF, d.w * SCALEF);
        qf[c] = t.v;
    }

    f32x4 o[8];
    #pragma unroll
    for (int dt = 0; dt < 8; ++dt) o[dt] = f32x4{0.f, 0.f, 0.f, 0.f};
    float mrun = -INFINITY, lsum = 0.f;

    for (int ch = 0; ch < nch; ++ch) {
        const int kvbase = isText ? ch * KVC
                         : (ch < 54 ? kvb0 + ch * KVC : IMG_LEN + (ch - 54) * KVC);
        __syncthreads();   // previous chunk's compute done before overwrite

        // ---- stage K chunk -> LDS [kv][d], coalesced global, conflict-free writes ----
        #pragma unroll
        for (int s = 0; s < 16; ++s) {
            int idx = tid + (s << 8);              // 0..4095 (pairs)
            int kv = idx >> 6, d2 = (idx & 63) << 1;
            float2 f = *(const float2*)(Kh + (size_t)(kvbase + kv) * DH + d2);
            *(unsigned*)&LK[kv * LKP + d2] = f2bf_pk(f.x, f.y);
        }
        // ---- stage V^T chunk -> LDS [d][kv], coalesced global reads ----
        #pragma unroll
        for (int s = 0; s < 16; ++s) {
            int idx = tid + (s << 8);              // 0..4095
            int kv2 = idx >> 7, d = idx & 127;
            int kv  = kv2 << 1;
            float va = Vh[(size_t)(kvbase + kv)     * DH + d];
            float vb = Vh[(size_t)(kvbase + kv + 1) * DH + d];
            *(unsigned*)&VT[d * VTP + kv] = f2bf_pk(va, vb);
        }
        __syncthreads();

        // ---- S^T = K * Q^T : lane holds S[q][kk], kk = kt*16 + g*4 + r ----
        f32x4 st[4];
        #pragma unroll
        for (int kt = 0; kt < 4; ++kt) st[kt] = f32x4{0.f, 0.f, 0.f, 0.f};
        #pragma unroll
        for (int c = 0; c < 4; ++c) {
            #pragma unroll
            for (int kt = 0; kt < 4; ++kt) {
                bf16x8 kf = *(const bf16x8*)&LK[(kt * 16 + q) * LKP + c * 32 + g * 8];
                st[kt] = __builtin_amdgcn_mfma_f32_16x16x32_bf16(kf, qf[c], st[kt], 0, 0, 0);
            }
        }

        // ---- online softmax (per lane: one q row; reduce across 4 lanes of same q) ----
        float cm = -INFINITY;
        #pragma unroll
        for (int kt = 0; kt < 4; ++kt)
            #pragma unroll
            for (int r = 0; r < 4; ++r) cm = fmaxf(cm, st[kt][r]);
        cm = fmaxf(cm, __shfl_xor(cm, 16));
        cm = fmaxf(cm, __shfl_xor(cm, 32));
        float mnew = fmaxf(mrun, cm);
        float sc = __expf(mrun - mnew);

        float p[4][4];
        float ps = 0.f;
        #pragma unroll
        for (int kt = 0; kt < 4; ++kt)
            #pragma unroll
            for (int r = 0; r < 4; ++r) {
                p[kt][r] = __expf(st[kt][r] - mnew);
                ps += p[kt][r];
            }
        ps += __shfl_xor(ps, 16);
        ps += __shfl_xor(ps, 32);
        lsum = lsum * sc + ps;
        mrun = mnew;
        #pragma unroll
        for (int dt = 0; dt < 8; ++dt) o[dt] *= sc;

        // ---- pack P to bf16 pairs; build P^T B-fragments via in-register shuffles ----
        unsigned pk[4][2];
        #pragma unroll
        for (int kt = 0; kt < 4; ++kt) {
            pk[kt][0] = f2bf_pk(p[kt][0], p[kt][1]);
            pk[kt][1] = f2bf_pk(p[kt][2], p[kt][3]);
        }
        const int gs2  = (g & 1) << 1;
        const int srcA = gs2 * 16 + q;          // source lanes holding needed kk pairs
        const int srcB = (gs2 + 1) * 16 + q;
        const bool hi  = (g >> 1) & 1;          // pick pk[2f+1] vs pk[2f]
        bf16x8 pf[2];
        #pragma unroll
        for (int f = 0; f < 2; ++f) {
            unsigned wA0 = __shfl((int)pk[2*f][0], srcA), xA0 = __shfl((int)pk[2*f+1][0], srcA);
            unsigned wA1 = __shfl((int)pk[2*f][1], srcA), xA1 = __shfl((int)pk[2*f+1][1], srcA);
            unsigned wB0 = __shfl((int)pk[2*f][0], srcB), xB0 = __shfl((int)pk[2*f+1][0], srcB);
            unsigned wB1 = __shfl((int)pk[2*f][1], srcB), xB1 = __shfl((int)pk[2*f+1][1], srcB);
            union { unsigned u[4]; bf16x8 v; } t;
            t.u[0] = hi ? xA0 : wA0;
            t.u[1] = hi ? xA1 : wA1;
            t.u[2] = hi ? xB0 : wB0;
            t.u[3] = hi ? xB1 : wB1;
            pf[f] = t.v;
        }

        // ---- O^T += V^T * P^T : lane holds O[q][d], d = dt*16 + g*4 + r ----
        #pragma unroll
        for (int f = 0; f < 2; ++f) {
            #pragma unroll
            for (int dt = 0; dt < 8; ++dt) {
                bf16x8 vf = *(const bf16x8*)&VT[(dt * 16 + q) * VTP + f * 32 + g * 8];
                o[dt] = __builtin_amdgcn_mfma_f32_16x16x32_bf16(vf, pf[f], o[dt], 0, 0, 0);
            }
        }
    }

    // ---- finalize: add 64 zero-pad keys (score 0) to denominator, divide, store ----
    const float inv = 1.f / (lsum + 64.f * __expf(-mrun));
    float* op = Og + hoff + (size_t)qrow * DH;
    #pragma unroll
    for (int dt = 0; dt < 8; ++dt) {
        float4 v;
        v.x = o[dt][0] * inv; v.y = o[dt][1] * inv;
        v.z = o[dt][2] * inv; v.w = o[dt][3] * inv;
        *(float4*)(op + dt * 16 + g * 4) = v;
    }
}

extern "C" void kernel_launch(void* const* d_in, const int* in_sizes, int n_in,
                              void* d_out, int out_size, void* d_ws, size_t ws_size,
                              hipStream_t stream) {
    const float* Qg = (const float*)d_in[0];
    const float* Kg = (const float*)d_in[1];
    const float* Vg = (const float*)d_in[2];
    float* Og = (float*)d_out;
    const int nblocks = NHEADS * NTXTT + NHEADS * NIMGT;   // 20 + 648 = 668
    hipLaunchKernelGGL(sta_attn, dim3(nblocks), dim3(256), 0, stream, Qg, Kg, Vg, Og);
}

// Round 2
// 311.399 us; speedup vs baseline: 1.5919x; 1.5919x over previous
//
#include <hip/hip_runtime.h>

// ---- problem constants (from reference) ----
#define SEQ      10688      // IMG_LEN + TEXT_LEN
#define IMG_LEN  10368      // 18*24*24
#define TEXT_LEN 320
#define DH       128
#define NHEADS   4
#define SLAB     3456       // 6*24*24 tokens per time-slab
#define KVC      64         // kv chunk rows
#define QTILE    64         // q rows per block (4 waves x 16)
#define NIMGT    162        // IMG_LEN/QTILE image q-tiles per head
#define NTXTT    5          // TEXT_LEN/QTILE text q-tiles per head
// (1/sqrt(128)) * log2(e): QK^T scores land in log2 domain -> exp2f softmax
#define SCALEL2E 0.12751744518924593f

typedef __bf16 bf16x8 __attribute__((ext_vector_type(8)));
typedef float  f32x4  __attribute__((ext_vector_type(4)));

__device__ __forceinline__ unsigned pk2bf(float a, float b) {
    union { __bf16 h[2]; unsigned u; } t;
    t.h[0] = (__bf16)a; t.h[1] = (__bf16)b;
    return t.u;
}

__global__ __launch_bounds__(256, 2) void sta_attn(const float* __restrict__ Qg,
                                                   const float* __restrict__ Kg,
                                                   const float* __restrict__ Vg,
                                                   float* __restrict__ Og) {
    // XOR-swizzled (16B slot ^ (row&7)), double-buffered, no pads.
    __shared__ __align__(16) unsigned short LK[2][KVC * DH];   // K  [kv][d]
    __shared__ __align__(16) unsigned short VT[2][DH * KVC];   // V^T [d][kv]

    const int tid  = threadIdx.x;
    const int lane = tid & 63;
    const int wv   = tid >> 6;
    const int q    = lane & 15;       // query row within wave's 16
    const int g    = lane >> 4;       // lane group 0..3
    const int swq  = (q & 7) << 3;    // element-granule read swizzle

    // block -> (head, qbase). Text tiles (167 chunks) first: longest poles start earliest.
    int b = blockIdx.x;
    int head, qbase, nch, kvb0;
    bool isText;
    if (b < NHEADS * NTXTT) {
        head = b / NTXTT; qbase = IMG_LEN + (b % NTXTT) * QTILE;
        isText = true;  nch = SEQ / KVC;  kvb0 = 0;
    } else {
        int bb = b - NHEADS * NTXTT;
        head = bb / NIMGT; qbase = (bb % NIMGT) * QTILE;
        isText = false; nch = 54 + 5;     // 54 slab chunks + 5 text chunks
        kvb0 = (qbase / SLAB) * SLAB;
    }

    const size_t hoff = (size_t)head * SEQ * DH;
    const float* Qh = Qg + hoff;
    const float* Kh = Kg + hoff;
    const float* Vh = Vg + hoff;

    // ---- Q fragments (B-operand layout), SCALE*log2e folded in ----
    const int qrow = qbase + wv * 16 + q;
    const float* qp = Qh + (size_t)qrow * DH;
    bf16x8 qf[4];
    #pragma unroll
    for (int c = 0; c < 4; ++c) {
        float4 a = *(const float4*)(qp + c * 32 + g * 8);
        float4 d = *(const float4*)(qp + c * 32 + g * 8 + 4);
        union { unsigned u[4]; bf16x8 v; } t;
        t.u[0] = pk2bf(a.x * SCALEL2E, a.y * SCALEL2E);
        t.u[1] = pk2bf(a.z * SCALEL2E, a.w * SCALEL2E);
        t.u[2] = pk2bf(d.x * SCALEL2E, d.y * SCALEL2E);
        t.u[3] = pk2bf(d.z * SCALEL2E, d.w * SCALEL2E);
        qf[c] = t.v;
    }

    f32x4 o[8];
    #pragma unroll
    for (int dt = 0; dt < 8; ++dt) o[dt] = f32x4{0.f, 0.f, 0.f, 0.f};
    float mrun = -INFINITY, lsum = 0.f;

    // staging registers (raw f32; converted at WRITE time so loads fly under compute)
    float4 kreg[8];
    float  vreg[4][8];

    auto kvaddr = [&](int ch) -> int {
        return isText ? ch * KVC
                      : (ch < 54 ? kvb0 + ch * KVC : IMG_LEN + (ch - 54) * KVC);
    };

    #define ISSUE(KVBASE)                                                        \
        {   const int _kb = (KVBASE);                                            \
            _Pragma("unroll")                                                    \
            for (int s = 0; s < 8; ++s) {                                        \
                int idx = tid + (s << 8);                                        \
                int kv = idx >> 5, dq = idx & 31;                                \
                kreg[s] = *(const float4*)(Kh + (size_t)(_kb + kv) * DH + dq*4); \
            }                                                                    \
            _Pragma("unroll")                                                    \
            for (int t = 0; t < 4; ++t) {                                        \
                int idx = tid + (t << 8);                                        \
                int d = idx & 127, kvb = idx >> 7;                               \
                const float* vp = Vh + (size_t)(_kb + kvb * 8) * DH + d;         \
                _Pragma("unroll")                                                \
                for (int j = 0; j < 8; ++j) vreg[t][j] = vp[j * DH];             \
            }                                                                    \
        }

    #define WRITE(BUF)                                                           \
        {   const int _bf = (BUF);                                               \
            _Pragma("unroll")                                                    \
            for (int s = 0; s < 8; ++s) {                                        \
                int idx = tid + (s << 8);                                        \
                int kv = idx >> 5, dq = idx & 31;                                \
                int off = kv * DH + ((dq * 4) ^ ((kv & 7) << 3));                \
                uint2 u; u.x = pk2bf(kreg[s].x, kreg[s].y);                      \
                         u.y = pk2bf(kreg[s].z, kreg[s].w);                      \
                *(uint2*)&LK[_bf][off] = u;                                      \
            }                                                                    \
            _Pragma("unroll")                                                    \
            for (int t = 0; t < 4; ++t) {                                        \
                int idx = tid + (t << 8);                                        \
                int d = idx & 127, kvb = idx >> 7;                               \
                int off = d * KVC + ((kvb * 8) ^ ((d & 7) << 3));                \
                uint4 u; u.x = pk2bf(vreg[t][0], vreg[t][1]);                    \
                         u.y = pk2bf(vreg[t][2], vreg[t][3]);                    \
                         u.z = pk2bf(vreg[t][4], vreg[t][5]);                    \
                         u.w = pk2bf(vreg[t][6], vreg[t][7]);                    \
                *(uint4*)&VT[_bf][off] = u;                                      \
            }                                                                    \
        }

    ISSUE(kvaddr(0));
    WRITE(0);
    __syncthreads();

    for (int ch = 0; ch < nch; ++ch) {
        const int buf = ch & 1;
        if (ch + 1 < nch) ISSUE(kvaddr(ch + 1));   // fly under this chunk's compute

        // ---- S^T = K * Q^T : lane holds S[q][kk], kk = kt*16 + g*4 + r ----
        f32x4 st[4];
        #pragma unroll
        for (int kt = 0; kt < 4; ++kt) st[kt] = f32x4{0.f, 0.f, 0.f, 0.f};
        #pragma unroll
        for (int c = 0; c < 4; ++c) {
            #pragma unroll
            for (int kt = 0; kt < 4; ++kt) {
                bf16x8 kf = *(const bf16x8*)&LK[buf][(kt*16 + q)*DH + ((c*32 + g*8) ^ swq)];
                st[kt] = __builtin_amdgcn_mfma_f32_16x16x32_bf16(kf, qf[c], st[kt], 0, 0, 0);
            }
        }

        // ---- online softmax (log2 domain) ----
        float cm = -INFINITY;
        #pragma unroll
        for (int kt = 0; kt < 4; ++kt)
            #pragma unroll
            for (int r = 0; r < 4; ++r) cm = fmaxf(cm, st[kt][r]);
        cm = fmaxf(cm, __shfl_xor(cm, 16));
        cm = fmaxf(cm, __shfl_xor(cm, 32));
        float mnew = fmaxf(mrun, cm);
        float sc = exp2f(mrun - mnew);

        float p[4][4];
        float ps = 0.f;
        #pragma unroll
        for (int kt = 0; kt < 4; ++kt)
            #pragma unroll
            for (int r = 0; r < 4; ++r) {
                p[kt][r] = exp2f(st[kt][r] - mnew);
                ps += p[kt][r];
            }
        ps += __shfl_xor(ps, 16);
        ps += __shfl_xor(ps, 32);
        lsum = lsum * sc + ps;
        mrun = mnew;
        #pragma unroll
        for (int dt = 0; dt < 8; ++dt) o[dt] *= sc;

        // ---- pack P to bf16 pairs; build P^T B-fragments via in-register shuffles ----
        unsigned pk[4][2];
        #pragma unroll
        for (int kt = 0; kt < 4; ++kt) {
            pk[kt][0] = pk2bf(p[kt][0], p[kt][1]);
            pk[kt][1] = pk2bf(p[kt][2], p[kt][3]);
        }
        const int gs2  = (g & 1) << 1;
        const int srcA = gs2 * 16 + q;
        const int srcB = (gs2 + 1) * 16 + q;
        const bool hi  = (g >> 1) & 1;
        bf16x8 pf[2];
        #pragma unroll
        for (int f = 0; f < 2; ++f) {
            unsigned wA0 = __shfl((int)pk[2*f][0], srcA), xA0 = __shfl((int)pk[2*f+1][0], srcA);
            unsigned wA1 = __shfl((int)pk[2*f][1], srcA), xA1 = __shfl((int)pk[2*f+1][1], srcA);
            unsigned wB0 = __shfl((int)pk[2*f][0], srcB), xB0 = __shfl((int)pk[2*f+1][0], srcB);
            unsigned wB1 = __shfl((int)pk[2*f][1], srcB), xB1 = __shfl((int)pk[2*f+1][1], srcB);
            union { unsigned u[4]; bf16x8 v; } t;
            t.u[0] = hi ? xA0 : wA0;
            t.u[1] = hi ? xA1 : wA1;
            t.u[2] = hi ? xB0 : wB0;
            t.u[3] = hi ? xB1 : wB1;
            pf[f] = t.v;
        }

        // ---- O^T += V^T * P^T : lane holds O[q][d], d = dt*16 + g*4 + r ----
        #pragma unroll
        for (int f = 0; f < 2; ++f) {
            #pragma unroll
            for (int dt = 0; dt < 8; ++dt) {
                bf16x8 vf = *(const bf16x8*)&VT[buf][(dt*16 + q)*KVC + ((f*32 + g*8) ^ swq)];
                o[dt] = __builtin_amdgcn_mfma_f32_16x16x32_bf16(vf, pf[f], o[dt], 0, 0, 0);
            }
        }

        if (ch + 1 < nch) {
            __syncthreads();       // all waves done reading buf (and buf^1 from ch-1)
            WRITE(buf ^ 1);        // vmcnt wait lands here, after loads flew under compute
            __syncthreads();
        }
    }

    // ---- finalize: 64 zero-pad keys contribute exp2(0 - mrun) each ----
    const float inv = 1.f / (lsum + 64.f * exp2f(-mrun));
    float* op = Og + hoff + (size_t)qrow * DH;
    #pragma unroll
    for (int dt = 0; dt < 8; ++dt) {
        float4 v;
        v.x = o[dt][0] * inv; v.y = o[dt][1] * inv;
        v.z = o[dt][2] * inv; v.w = o[dt][3] * inv;
        *(float4*)(op + dt * 16 + g * 4) = v;
    }
    #undef ISSUE
    #undef WRITE
}

extern "C" void kernel_launch(void* const* d_in, const int* in_sizes, int n_in,
                              void* d_out, int out_size, void* d_ws, size_t ws_size,
                              hipStream_t stream) {
    const float* Qg = (const float*)d_in[0];
    const float* Kg = (const float*)d_in[1];
    const float* Vg = (const float*)d_in[2];
    float* Og = (float*)d_out;
    const int nblocks = NHEADS * NTXTT + NHEADS * NIMGT;   // 20 + 648 = 668
    hipLaunchKernelGGL(sta_attn, dim3(nblocks), dim3(256), 0, stream, Qg, Kg, Vg, Og);
}